// Round 8
// baseline (348.312 us; speedup 1.0000x reference)
//
#include <hip/hip_runtime.h>
#include <hip/hip_fp16.h>

#define NDIM 64
#define RS2 65     // LDS row stride: 2-way bank alias only (free per m136)
#define MAXNB 512  // supports N <= 131072 (bucket = dst>>8); this problem: N=100000 -> 391

// native vector types for __builtin_nontemporal_* (HIP float4 is a class -> rejected)
typedef float  vf4 __attribute__((ext_vector_type(4)));
typedef unsigned int vu2 __attribute__((ext_vector_type(2)));

// ---------------- BN fold: W1f = W1 * s, b1f = (b1-mean)*s + beta ----------------
__global__ __launch_bounds__(256) void fold_bn_kernel(
    const float* __restrict__ W1, const float* __restrict__ b1,
    const float* __restrict__ gamma, const float* __restrict__ beta,
    const float* __restrict__ mean, const float* __restrict__ var,
    float* __restrict__ W1f, float* __restrict__ b1f, int LD)
{
    int tid = blockIdx.x * blockDim.x + threadIdx.x;
    if (tid >= LD) return;
    float s = gamma[tid] * rsqrtf(var[tid] + 1e-5f);
    b1f[tid] = (b1[tid] - mean[tid]) * s + beta[tid];
    int l = tid >> 6, c = tid & 63;
    const float* wsrc = W1 + (size_t)l * 4096;
    float* wdst = W1f + (size_t)l * 4096;
    for (int k = 0; k < 64; ++k) wdst[k * 64 + c] = wsrc[k * 64 + c] * s;
}

// ---------------- x (fp32) -> fp16 rows for the gather ----------------
__global__ __launch_bounds__(256) void to_half_kernel(
    const float* __restrict__ x, __half* __restrict__ x16, int n4)
{
    int tid = blockIdx.x * blockDim.x + threadIdx.x;
    if (tid >= n4) return;
    float4 v = *(const float4*)(x + (size_t)tid * 4);
    __half2* dp = (__half2*)(x16 + (size_t)tid * 4);
    dp[0] = __floats2half2_rn(v.x, v.y);
    dp[1] = __floats2half2_rn(v.z, v.w);
}

// ---------------- CSR build, two-level LDS counting sort ----------------
__global__ __launch_bounds__(256) void bucket_count_kernel(
    const int* __restrict__ dst, int* __restrict__ bcnt, int E, int NBb)
{
    __shared__ int hist[MAXNB];
    for (int i = threadIdx.x; i < NBb; i += 256) hist[i] = 0;
    __syncthreads();
    int start = blockIdx.x * blockDim.x + threadIdx.x;
    int stride = gridDim.x * blockDim.x;
    for (int e = start; e < E; e += stride)
        atomicAdd(&hist[dst[e] >> 8], 1);          // LDS atomic: on-CU
    __syncthreads();
    for (int i = threadIdx.x; i < NBb; i += 256) {
        int v = hist[i];
        if (v) atomicAdd(&bcnt[i], v);
    }
}

__global__ __launch_bounds__(512) void bucket_scan_kernel(
    const int* __restrict__ bcnt, int* __restrict__ bbase,
    int* __restrict__ bcursor, int NBb)
{
    __shared__ int sd[512];
    int t = threadIdx.x;
    int v = (t < NBb) ? bcnt[t] : 0;
    sd[t] = v;
    __syncthreads();
    for (int d = 1; d < 512; d <<= 1) {
        int x = sd[t];
        int y = (t >= d) ? sd[t - d] : 0;
        __syncthreads();
        sd[t] = x + y;
        __syncthreads();
    }
    int excl = sd[t] - v;
    if (t < NBb) { bbase[t] = excl; bcursor[t] = excl; }
    if (t == NBb - 1) bbase[NBb] = sd[t];
}

__global__ __launch_bounds__(256) void bucket_scatter_kernel(
    const int* __restrict__ src, const int* __restrict__ dst,
    int* __restrict__ bcursor, unsigned int* __restrict__ packed, int E, int NBb)
{
    __shared__ int hist[MAXNB];
    __shared__ int sbase[MAXNB];
    for (int i = threadIdx.x; i < NBb; i += 256) hist[i] = 0;
    __syncthreads();
    int start = blockIdx.x * blockDim.x + threadIdx.x;
    int stride = gridDim.x * blockDim.x;
    for (int e = start; e < E; e += stride)
        atomicAdd(&hist[dst[e] >> 8], 1);
    __syncthreads();
    for (int i = threadIdx.x; i < NBb; i += 256) {
        int v = hist[i];
        sbase[i] = v ? atomicAdd(&bcursor[i], v) : 0;
    }
    __syncthreads();
    for (int i = threadIdx.x; i < NBb; i += 256) hist[i] = 0;  // reuse as cursor
    __syncthreads();
    for (int e = start; e < E; e += stride) {
        int d = dst[e];
        int b = d >> 8;
        int r = atomicAdd(&hist[b], 1);            // LDS rank
        packed[sbase[b] + r] = (unsigned)src[e] | ((unsigned)(d & 255) << 24);
    }
}

__global__ __launch_bounds__(256) void bucket_csr_kernel(
    const unsigned int* __restrict__ packed, const int* __restrict__ bbase,
    int* __restrict__ ssrc, int* __restrict__ offs, int* __restrict__ ends, int N)
{
    __shared__ int hist[256], scan[256], cur[256];
    int b = blockIdx.x;
    int base = bbase[b], cnt = bbase[b + 1] - base;
    int t = threadIdx.x;
    hist[t] = 0;
    __syncthreads();
    for (int i = t; i < cnt; i += 256)
        atomicAdd(&hist[packed[base + i] >> 24], 1);
    __syncthreads();
    int v = hist[t];
    scan[t] = v;
    __syncthreads();
    for (int d = 1; d < 256; d <<= 1) {
        int x = scan[t];
        int y = (t >= d) ? scan[t - d] : 0;
        __syncthreads();
        scan[t] = x + y;
        __syncthreads();
    }
    int e0 = base + scan[t] - v;
    cur[t] = e0;
    int node = b * 256 + t;
    if (node < N) { offs[node] = e0; ends[node] = e0 + v; }
    __syncthreads();
    for (int i = t; i < cnt; i += 256) {
        unsigned p = packed[base + i];
        int pos = atomicAdd(&cur[p >> 24], 1);
        ssrc[pos] = (int)(p & 0xFFFFFF);
    }
}

// ---------------- fused GIN layer: gather -> LDS tile -> MLP -> jk/hout ------------
// gather: 8 lane-groups of 8, dwordx4 fp16x8 loads, 16 edges in flight
__device__ inline void add_h8(vf4 raw, float* acc) {
    float r0 = raw.x, r1 = raw.y, r2 = raw.z, r3 = raw.w;
    __half2 h0 = *(__half2*)&r0, h1 = *(__half2*)&r1;
    __half2 h2 = *(__half2*)&r2, h3 = *(__half2*)&r3;
    float2 f;
    f = __half22float2(h0); acc[0] += f.x; acc[1] += f.y;
    f = __half22float2(h1); acc[2] += f.x; acc[3] += f.y;
    f = __half22float2(h2); acc[4] += f.x; acc[5] += f.y;
    f = __half22float2(h3); acc[6] += f.x; acc[7] += f.y;
}

__global__ __launch_bounds__(256, 6) void gin_layer_kernel(
    const __half* __restrict__ hin, __half* __restrict__ hout,
    float* __restrict__ jk,
    const int* __restrict__ offs, const int* __restrict__ ends,
    const int* __restrict__ ssrc,
    const float* __restrict__ W1f, const float* __restrict__ b1f,
    const float* __restrict__ W2, const float* __restrict__ b2,
    int N, int relu_out, int first, int write_h)
{
    __shared__ float lds[64 * RS2];   // 16.6 KB: pre tile, then z, then h
    __shared__ int sOffs[64], sEnds[64];
    int t = threadIdx.x;
    int lane = t & 63;
    int w = t >> 6;
    int row0 = blockIdx.x * 64;

    if (t < 64) {
        int node = row0 + t;
        sOffs[t] = (node < N) ? offs[node] : 0;
        sEnds[t] = (node < N) ? ends[node] : 0;
    }
    __syncthreads();

    // ---- gather phase: wave w produces rows w*16 .. w*16+15 of the pre tile ----
    int grp = lane >> 3;   // edge slot within an 8-edge bundle
    int q   = lane & 7;    // fp16x8 (16B) chunk of the 128B row
    for (int i = 0; i < 16; ++i) {
        int rl = w * 16 + i;
        int node = row0 + rl;
        if (node >= N) break;
        int beg = sOffs[rl], end = sEnds[rl];

        float acc[8], acc2[8];
        #pragma unroll
        for (int c = 0; c < 8; ++c) { acc[c] = 0.f; acc2[c] = 0.f; }

        for (int e = beg; e < end; e += 16) {
            int i1 = e + grp, i2 = e + grp + 8;
            int j1 = (i1 < end) ? __builtin_nontemporal_load(ssrc + i1) : -1;
            int j2 = (i2 < end) ? __builtin_nontemporal_load(ssrc + i2) : -1;
            if (j1 >= 0)
                add_h8(*(const vf4*)(hin + (size_t)j1 * NDIM + q * 8), acc);
            if (j2 >= 0)
                add_h8(*(const vf4*)(hin + (size_t)j2 * NDIM + q * 8), acc2);
        }
        #pragma unroll
        for (int c = 0; c < 8; ++c) acc[c] += acc2[c];
        #pragma unroll
        for (int c = 0; c < 8; ++c) acc[c] += __shfl_xor(acc[c], 8, 64);
        #pragma unroll
        for (int c = 0; c < 8; ++c) acc[c] += __shfl_xor(acc[c], 16, 64);
        #pragma unroll
        for (int c = 0; c < 8; ++c) acc[c] += __shfl_xor(acc[c], 32, 64);

        if (grp == 0) {   // lanes 0..7 hold the final row: self add + LDS store
            float self[8];
            #pragma unroll
            for (int c = 0; c < 8; ++c) self[c] = 0.f;
            add_h8(*(const vf4*)(hin + (size_t)node * NDIM + q * 8), self);
            float* p = lds + rl * RS2 + q * 8;
            #pragma unroll
            for (int c = 0; c < 8; ++c) p[c] = acc[c] + self[c];
        }
    }
    __syncthreads();

    // ---- MLP phase: column-split, wave w covers cols [16w, 16w+16) ----
    int c0 = __builtin_amdgcn_readfirstlane(w * 16);
    const float* myRow = lds + lane * RS2;
    float acc[16];
    #pragma unroll
    for (int c = 0; c < 16; ++c) acc[c] = 0.f;
    #pragma unroll 4
    for (int k = 0; k < NDIM; ++k) {
        float p = myRow[k];
        const float* Wk = W1f + k * NDIM + c0;    // wave-uniform -> s_load
        #pragma unroll
        for (int c = 0; c < 16; ++c) acc[c] = fmaf(p, Wk[c], acc[c]);
    }
    __syncthreads();
    #pragma unroll
    for (int c = 0; c < 16; ++c)
        lds[lane * RS2 + c0 + c] = fmaxf(acc[c] + b1f[c0 + c], 0.f);
    __syncthreads();

    #pragma unroll
    for (int c = 0; c < 16; ++c) acc[c] = 0.f;
    #pragma unroll 4
    for (int k = 0; k < NDIM; ++k) {
        float p = myRow[k];
        const float* Wk = W2 + k * NDIM + c0;
        #pragma unroll
        for (int c = 0; c < 16; ++c) acc[c] = fmaf(p, Wk[c], acc[c]);
    }
    __syncthreads();
    #pragma unroll
    for (int c = 0; c < 16; ++c) {
        float hv = acc[c] + b2[c0 + c];
        if (relu_out) hv = fmaxf(hv, 0.f);
        lds[lane * RS2 + c0 + c] = hv;
    }
    __syncthreads();

    // ---- writeback: jk (fp32) + next-layer h (fp16) — all non-temporal streams ----
    #pragma unroll
    for (int it = 0; it < 4; ++it) {
        int f4 = it * 256 + t;
        int r = f4 >> 4, c4 = f4 & 15;
        int grow = row0 + r;
        if (grow >= N) continue;
        const float* p = lds + r * RS2 + c4 * 4;
        vf4 hv;
        hv.x = p[0]; hv.y = p[1]; hv.z = p[2]; hv.w = p[3];
        if (write_h) {
            __half2 a = __floats2half2_rn(hv.x, hv.y);
            __half2 b = __floats2half2_rn(hv.z, hv.w);
            vu2 pk;
            pk.x = *(unsigned*)&a;
            pk.y = *(unsigned*)&b;
            __builtin_nontemporal_store(pk, (vu2*)(hout + (size_t)grow * NDIM + c4 * 4));
        }
        vf4 jv;
        if (first) jv = hv;
        else {
            vf4 o = __builtin_nontemporal_load(
                (const vf4*)(jk + (size_t)grow * NDIM + c4 * 4));
            jv = o + hv;
        }
        __builtin_nontemporal_store(jv, (vf4*)(jk + (size_t)grow * NDIM + c4 * 4));
    }
}

extern "C" void kernel_launch(void* const* d_in, const int* in_sizes, int n_in,
                              void* d_out, int out_size, void* d_ws, size_t ws_size,
                              hipStream_t stream) {
    const float* x     = (const float*)d_in[0];
    const int*   src   = (const int*)  d_in[1];
    const int*   dst   = (const int*)  d_in[2];
    const float* W1    = (const float*)d_in[3];
    const float* b1    = (const float*)d_in[4];
    const float* gamma = (const float*)d_in[5];
    const float* beta  = (const float*)d_in[6];
    const float* mean  = (const float*)d_in[7];
    const float* var   = (const float*)d_in[8];
    const float* W2    = (const float*)d_in[9];
    const float* b2    = (const float*)d_in[10];

    int N = in_sizes[0] / NDIM;
    int E = in_sizes[1];
    int L = in_sizes[3] / (NDIM * NDIM);
    int NBb = (N + 255) >> 8;            // buckets of 256 nodes
    float* out = (float*)d_out;

    char* w = (char*)d_ws;
    size_t off = 0;
    auto carve = [&](size_t bytes) -> void* {
        void* p = w + off;
        off += (bytes + 255) & ~(size_t)255;
        return p;
    };
    __half* h16A    = (__half*)carve((size_t)N * NDIM * 2);   // ping
    __half* h16B    = (__half*)carve((size_t)N * NDIM * 2);   // pong
    int*    ssrc    = (int*)   carve((size_t)E * 4);
    unsigned int* packed = (unsigned int*)carve((size_t)E * 4);
    int*    offs    = (int*)   carve((size_t)N * 4);
    int*    ends    = (int*)   carve((size_t)N * 4);
    int*    bcnt    = (int*)   carve((size_t)(MAXNB + 1) * 4);
    int*    bbase   = (int*)   carve((size_t)(MAXNB + 1) * 4);
    int*    bcursor = (int*)   carve((size_t)MAXNB * 4);
    float*  W1f     = (float*) carve((size_t)L * NDIM * NDIM * 4);
    float*  b1f     = (float*) carve((size_t)L * NDIM * 4);

    (void)hipMemsetAsync(bcnt, 0, (size_t)(MAXNB + 1) * 4, stream);
    fold_bn_kernel<<<(L * NDIM + 255) / 256, 256, 0, stream>>>(
        W1, b1, gamma, beta, mean, var, W1f, b1f, L * NDIM);
    to_half_kernel<<<(N * NDIM / 4 + 255) / 256, 256, 0, stream>>>(x, h16A, N * NDIM / 4);
    bucket_count_kernel<<<256, 256, 0, stream>>>(dst, bcnt, E, NBb);
    bucket_scan_kernel<<<1, 512, 0, stream>>>(bcnt, bbase, bcursor, NBb);
    bucket_scatter_kernel<<<256, 256, 0, stream>>>(src, dst, bcursor, packed, E, NBb);
    bucket_csr_kernel<<<NBb, 256, 0, stream>>>(packed, bbase, ssrc, offs, ends, N);

    const __half* hin = h16A;
    __half* hout = h16B;
    for (int l = 0; l < L; ++l) {
        gin_layer_kernel<<<(N + 63) / 64, 256, 0, stream>>>(
            hin, hout, out, offs, ends, ssrc,
            W1f + (size_t)l * NDIM * NDIM, b1f + (size_t)l * NDIM,
            W2  + (size_t)l * NDIM * NDIM, b2  + (size_t)l * NDIM,
            N, (l < L - 1) ? 1 : 0, (l == 0) ? 1 : 0, (l < L - 1) ? 1 : 0);
        const __half* tmp = hin;
        hin = hout;
        hout = (__half*)tmp;
    }
}

// Round 10
// 339.310 us; speedup vs baseline: 1.0265x; 1.0265x over previous
//
#include <hip/hip_runtime.h>
#include <hip/hip_fp16.h>

#define NDIM 64
#define RS2 65     // LDS row stride: 2-way bank alias only (free per m136)
#define MAXNB 512  // supports N <= 131072 (bucket = dst>>8); this problem: N=100000 -> 391

// native vector types for __builtin_nontemporal_* (HIP float4 is a class -> rejected)
typedef float        vf4 __attribute__((ext_vector_type(4)));
typedef unsigned int vu2 __attribute__((ext_vector_type(2)));

__device__ inline __half2 u2h2(unsigned u) { return *(__half2*)&u; }

// ---------------- BN fold: W1f = W1 * s, b1f = (b1-mean)*s + beta ----------------
__global__ __launch_bounds__(256) void fold_bn_kernel(
    const float* __restrict__ W1, const float* __restrict__ b1,
    const float* __restrict__ gamma, const float* __restrict__ beta,
    const float* __restrict__ mean, const float* __restrict__ var,
    float* __restrict__ W1f, float* __restrict__ b1f, int LD)
{
    int tid = blockIdx.x * blockDim.x + threadIdx.x;
    if (tid >= LD) return;
    float s = gamma[tid] * rsqrtf(var[tid] + 1e-5f);
    b1f[tid] = (b1[tid] - mean[tid]) * s + beta[tid];
    int l = tid >> 6, c = tid & 63;
    const float* wsrc = W1 + (size_t)l * 4096;
    float* wdst = W1f + (size_t)l * 4096;
    for (int k = 0; k < 64; ++k) wdst[k * 64 + c] = wsrc[k * 64 + c] * s;
}

// ---------------- x (fp32) -> fp16 rows for the gather ----------------
__global__ __launch_bounds__(256) void to_half_kernel(
    const float* __restrict__ x, __half* __restrict__ x16, int n4)
{
    int tid = blockIdx.x * blockDim.x + threadIdx.x;
    if (tid >= n4) return;
    float4 v = *(const float4*)(x + (size_t)tid * 4);
    __half2* dp = (__half2*)(x16 + (size_t)tid * 4);
    dp[0] = __floats2half2_rn(v.x, v.y);
    dp[1] = __floats2half2_rn(v.z, v.w);
}

// ---------------- CSR build, two-level LDS counting sort ----------------
__global__ __launch_bounds__(256) void bucket_count_kernel(
    const int* __restrict__ dst, int* __restrict__ bcnt, int E, int NBb)
{
    __shared__ int hist[MAXNB];
    for (int i = threadIdx.x; i < NBb; i += 256) hist[i] = 0;
    __syncthreads();
    int start = blockIdx.x * blockDim.x + threadIdx.x;
    int stride = gridDim.x * blockDim.x;
    for (int e = start; e < E; e += stride)
        atomicAdd(&hist[dst[e] >> 8], 1);          // LDS atomic: on-CU
    __syncthreads();
    for (int i = threadIdx.x; i < NBb; i += 256) {
        int v = hist[i];
        if (v) atomicAdd(&bcnt[i], v);
    }
}

__global__ __launch_bounds__(512) void bucket_scan_kernel(
    const int* __restrict__ bcnt, int* __restrict__ bbase,
    int* __restrict__ bcursor, int NBb)
{
    __shared__ int sd[512];
    int t = threadIdx.x;
    int v = (t < NBb) ? bcnt[t] : 0;
    sd[t] = v;
    __syncthreads();
    for (int d = 1; d < 512; d <<= 1) {
        int x = sd[t];
        int y = (t >= d) ? sd[t - d] : 0;
        __syncthreads();
        sd[t] = x + y;
        __syncthreads();
    }
    int excl = sd[t] - v;
    if (t < NBb) { bbase[t] = excl; bcursor[t] = excl; }
    if (t == NBb - 1) bbase[NBb] = sd[t];
}

__global__ __launch_bounds__(256) void bucket_scatter_kernel(
    const int* __restrict__ src, const int* __restrict__ dst,
    int* __restrict__ bcursor, unsigned int* __restrict__ packed, int E, int NBb)
{
    __shared__ int hist[MAXNB];
    __shared__ int sbase[MAXNB];
    for (int i = threadIdx.x; i < NBb; i += 256) hist[i] = 0;
    __syncthreads();
    int start = blockIdx.x * blockDim.x + threadIdx.x;
    int stride = gridDim.x * blockDim.x;
    for (int e = start; e < E; e += stride)
        atomicAdd(&hist[dst[e] >> 8], 1);
    __syncthreads();
    for (int i = threadIdx.x; i < NBb; i += 256) {
        int v = hist[i];
        sbase[i] = v ? atomicAdd(&bcursor[i], v) : 0;
    }
    __syncthreads();
    for (int i = threadIdx.x; i < NBb; i += 256) hist[i] = 0;  // reuse as cursor
    __syncthreads();
    for (int e = start; e < E; e += stride) {
        int d = dst[e];
        int b = d >> 8;
        int r = atomicAdd(&hist[b], 1);            // LDS rank
        packed[sbase[b] + r] = (unsigned)src[e] | ((unsigned)(d & 255) << 24);
    }
}

__global__ __launch_bounds__(256) void bucket_csr_kernel(
    const unsigned int* __restrict__ packed, const int* __restrict__ bbase,
    int* __restrict__ ssrc, int* __restrict__ offs, int* __restrict__ ends, int N)
{
    __shared__ int hist[256], scan[256], cur[256];
    int b = blockIdx.x;
    int base = bbase[b], cnt = bbase[b + 1] - base;
    int t = threadIdx.x;
    hist[t] = 0;
    __syncthreads();
    for (int i = t; i < cnt; i += 256)
        atomicAdd(&hist[packed[base + i] >> 24], 1);
    __syncthreads();
    int v = hist[t];
    scan[t] = v;
    __syncthreads();
    for (int d = 1; d < 256; d <<= 1) {
        int x = scan[t];
        int y = (t >= d) ? scan[t - d] : 0;
        __syncthreads();
        scan[t] = x + y;
        __syncthreads();
    }
    int e0 = base + scan[t] - v;
    cur[t] = e0;
    int node = b * 256 + t;
    if (node < N) { offs[node] = e0; ends[node] = e0 + v; }
    __syncthreads();
    for (int i = t; i < cnt; i += 256) {
        unsigned p = packed[base + i];
        int pos = atomicAdd(&cur[p >> 24], 1);
        ssrc[pos] = (int)(p & 0xFFFFFF);
    }
}

// ---------------- fused GIN layer: gather -> LDS tile -> MLP -> jk/hout ------------
__device__ inline __half2 shfl_xor_h2(__half2 v, int m) {
    int u = *(int*)&v;
    u = __shfl_xor(u, m, 64);
    return *(__half2*)&u;
}

__global__ __launch_bounds__(256, 6) void gin_layer_kernel(
    const __half* __restrict__ hin, __half* __restrict__ hout,
    float* __restrict__ jk,
    const int* __restrict__ offs, const int* __restrict__ ends,
    const int* __restrict__ ssrc,
    const float* __restrict__ W1f, const float* __restrict__ b1f,
    const float* __restrict__ W2, const float* __restrict__ b2,
    int N, int relu_out, int first, int write_h)
{
    __shared__ float lds[64 * RS2];   // 16.6 KB: pre tile, then z, then h
    __shared__ int sOffs[64], sEnds[64];
    int t = threadIdx.x;
    int lane = t & 63;
    int w = t >> 6;
    int row0 = blockIdx.x * 64;

    if (t < 64) {
        int node = row0 + t;
        sOffs[t] = (node < N) ? offs[node] : 0;
        sEnds[t] = (node < N) ? ends[node] : 0;
    }
    __syncthreads();

    // ---- gather phase: wave w produces rows w*16 .. w*16+15 of the pre tile ----
    // 4 lane-groups of 16; 8B fp16x4 loads; packed fp16 accumulation (v_pk_add_f16)
    int grp = lane >> 4;   // edge slot within a 4-edge bundle
    int q   = lane & 15;   // fp16x4 (8B) chunk of the 128B row
    const __half2 h2zero = __floats2half2_rn(0.f, 0.f);
    for (int i = 0; i < 16; ++i) {
        int rl = w * 16 + i;
        int node = row0 + rl;
        if (node >= N) break;
        int beg = sOffs[rl], end = sEnds[rl];

        __half2 a1a = h2zero, a1b = h2zero, a2a = h2zero, a2b = h2zero;
        for (int e = beg; e < end; e += 8) {
            int i1 = e + grp, i2 = e + grp + 4;
            int j1 = (i1 < end) ? ssrc[i1] : -1;
            int j2 = (i2 < end) ? ssrc[i2] : -1;
            if (j1 >= 0) {
                vu2 raw = *(const vu2*)(hin + (size_t)j1 * NDIM + q * 4);
                unsigned ux = raw.x, uy = raw.y;
                a1a = __hadd2(a1a, u2h2(ux));
                a1b = __hadd2(a1b, u2h2(uy));
            }
            if (j2 >= 0) {
                vu2 raw = *(const vu2*)(hin + (size_t)j2 * NDIM + q * 4);
                unsigned ux = raw.x, uy = raw.y;
                a2a = __hadd2(a2a, u2h2(ux));
                a2b = __hadd2(a2b, u2h2(uy));
            }
        }
        a1a = __hadd2(a1a, a2a);
        a1b = __hadd2(a1b, a2b);
        a1a = __hadd2(a1a, shfl_xor_h2(a1a, 16));
        a1b = __hadd2(a1b, shfl_xor_h2(a1b, 16));
        a1a = __hadd2(a1a, shfl_xor_h2(a1a, 32));
        a1b = __hadd2(a1b, shfl_xor_h2(a1b, 32));

        if (grp == 0) {   // lanes 0..15 hold the final row: self add, cvt, LDS store
            vu2 raw = *(const vu2*)(hin + (size_t)node * NDIM + q * 4);
            unsigned ux = raw.x, uy = raw.y;
            a1a = __hadd2(a1a, u2h2(ux));
            a1b = __hadd2(a1b, u2h2(uy));
            float2 fa = __half22float2(a1a);
            float2 fb = __half22float2(a1b);
            float* p = lds + rl * RS2 + q * 4;
            p[0] = fa.x; p[1] = fa.y; p[2] = fb.x; p[3] = fb.y;
        }
    }
    __syncthreads();

    // ---- MLP phase: column-split, wave w covers cols [16w, 16w+16) ----
    int c0 = __builtin_amdgcn_readfirstlane(w * 16);
    const float* myRow = lds + lane * RS2;
    float acc[16];
    #pragma unroll
    for (int c = 0; c < 16; ++c) acc[c] = 0.f;
    #pragma unroll 4
    for (int k = 0; k < NDIM; ++k) {
        float p = myRow[k];
        const float* Wk = W1f + k * NDIM + c0;    // wave-uniform -> s_load
        #pragma unroll
        for (int c = 0; c < 16; ++c) acc[c] = fmaf(p, Wk[c], acc[c]);
    }
    __syncthreads();
    #pragma unroll
    for (int c = 0; c < 16; ++c)
        lds[lane * RS2 + c0 + c] = fmaxf(acc[c] + b1f[c0 + c], 0.f);
    __syncthreads();

    #pragma unroll
    for (int c = 0; c < 16; ++c) acc[c] = 0.f;
    #pragma unroll 4
    for (int k = 0; k < NDIM; ++k) {
        float p = myRow[k];
        const float* Wk = W2 + k * NDIM + c0;
        #pragma unroll
        for (int c = 0; c < 16; ++c) acc[c] = fmaf(p, Wk[c], acc[c]);
    }
    __syncthreads();
    #pragma unroll
    for (int c = 0; c < 16; ++c) {
        float hv = acc[c] + b2[c0 + c];
        if (relu_out) hv = fmaxf(hv, 0.f);
        lds[lane * RS2 + c0 + c] = hv;
    }
    __syncthreads();

    // ---- writeback: jk (fp32) + next-layer h (fp16); NT stores only ----
    #pragma unroll
    for (int it = 0; it < 4; ++it) {
        int f4 = it * 256 + t;
        int r = f4 >> 4, c4 = f4 & 15;
        int grow = row0 + r;
        if (grow >= N) continue;
        const float* p = lds + r * RS2 + c4 * 4;
        vf4 hv;
        hv.x = p[0]; hv.y = p[1]; hv.z = p[2]; hv.w = p[3];
        if (write_h) {
            __half2 a = __floats2half2_rn(hv.x, hv.y);
            __half2 b = __floats2half2_rn(hv.z, hv.w);
            vu2 pk;
            pk.x = *(unsigned*)&a;
            pk.y = *(unsigned*)&b;
            __builtin_nontemporal_store(pk, (vu2*)(hout + (size_t)grow * NDIM + c4 * 4));
        }
        vf4 jv;
        if (first) jv = hv;
        else {
            vf4 o = *(const vf4*)(jk + (size_t)grow * NDIM + c4 * 4);
            jv = o + hv;
        }
        __builtin_nontemporal_store(jv, (vf4*)(jk + (size_t)grow * NDIM + c4 * 4));
    }
}

extern "C" void kernel_launch(void* const* d_in, const int* in_sizes, int n_in,
                              void* d_out, int out_size, void* d_ws, size_t ws_size,
                              hipStream_t stream) {
    const float* x     = (const float*)d_in[0];
    const int*   src   = (const int*)  d_in[1];
    const int*   dst   = (const int*)  d_in[2];
    const float* W1    = (const float*)d_in[3];
    const float* b1    = (const float*)d_in[4];
    const float* gamma = (const float*)d_in[5];
    const float* beta  = (const float*)d_in[6];
    const float* mean  = (const float*)d_in[7];
    const float* var   = (const float*)d_in[8];
    const float* W2    = (const float*)d_in[9];
    const float* b2    = (const float*)d_in[10];

    int N = in_sizes[0] / NDIM;
    int E = in_sizes[1];
    int L = in_sizes[3] / (NDIM * NDIM);
    int NBb = (N + 255) >> 8;            // buckets of 256 nodes
    float* out = (float*)d_out;

    char* w = (char*)d_ws;
    size_t off = 0;
    auto carve = [&](size_t bytes) -> void* {
        void* p = w + off;
        off += (bytes + 255) & ~(size_t)255;
        return p;
    };
    __half* h16A    = (__half*)carve((size_t)N * NDIM * 2);   // ping
    __half* h16B    = (__half*)carve((size_t)N * NDIM * 2);   // pong
    int*    ssrc    = (int*)   carve((size_t)E * 4);
    unsigned int* packed = (unsigned int*)carve((size_t)E * 4);
    int*    offs    = (int*)   carve((size_t)N * 4);
    int*    ends    = (int*)   carve((size_t)N * 4);
    int*    bcnt    = (int*)   carve((size_t)(MAXNB + 1) * 4);
    int*    bbase   = (int*)   carve((size_t)(MAXNB + 1) * 4);
    int*    bcursor = (int*)   carve((size_t)MAXNB * 4);
    float*  W1f     = (float*) carve((size_t)L * NDIM * NDIM * 4);
    float*  b1f     = (float*) carve((size_t)L * NDIM * 4);

    (void)hipMemsetAsync(bcnt, 0, (size_t)(MAXNB + 1) * 4, stream);
    fold_bn_kernel<<<(L * NDIM + 255) / 256, 256, 0, stream>>>(
        W1, b1, gamma, beta, mean, var, W1f, b1f, L * NDIM);
    to_half_kernel<<<(N * NDIM / 4 + 255) / 256, 256, 0, stream>>>(x, h16A, N * NDIM / 4);
    bucket_count_kernel<<<256, 256, 0, stream>>>(dst, bcnt, E, NBb);
    bucket_scan_kernel<<<1, 512, 0, stream>>>(bcnt, bbase, bcursor, NBb);
    bucket_scatter_kernel<<<256, 256, 0, stream>>>(src, dst, bcursor, packed, E, NBb);
    bucket_csr_kernel<<<NBb, 256, 0, stream>>>(packed, bbase, ssrc, offs, ends, N);

    const __half* hin = h16A;
    __half* hout = h16B;
    for (int l = 0; l < L; ++l) {
        gin_layer_kernel<<<(N + 63) / 64, 256, 0, stream>>>(
            hin, hout, out, offs, ends, ssrc,
            W1f + (size_t)l * NDIM * NDIM, b1f + (size_t)l * NDIM,
            W2  + (size_t)l * NDIM * NDIM, b2  + (size_t)l * NDIM,
            N, (l < L - 1) ? 1 : 0, (l == 0) ? 1 : 0, (l < L - 1) ? 1 : 0);
        const __half* tmp = hin;
        hin = hout;
        hout = (__half*)tmp;
    }
}